// Round 6
// baseline (7105.658 us; speedup 1.0000x reference)
//
#include <hip/hip_runtime.h>
#include <cstdint>
#include <cstddef>

#define Dm 768
#define Hh 12
#define DHd 64
#define Ll 12
#define Vv 50257
#define Tt 4096
#define Ff 3072
#define ETA (1.0f/16.0f)

typedef __attribute__((ext_vector_type(8))) short bf16x8;
typedef __attribute__((ext_vector_type(8))) unsigned short ushort8;
typedef __attribute__((ext_vector_type(4))) float f32x4;

static __device__ __forceinline__ unsigned short f2bf(float f){
  union { float f; unsigned int u; } v; v.f = f;
  unsigned int r = v.u + 0x7fffu + ((v.u >> 16) & 1u);
  return (unsigned short)(r >> 16);
}
// returns (hi<<16)|lo : hi=bf16(f), lo=bf16(f - hi)
static __device__ __forceinline__ uint32_t split_bf(float f){
  const unsigned short h = f2bf(f);
  union { uint32_t u; float f; } vh; vh.u = ((uint32_t)h) << 16;
  const unsigned short l = f2bf(f - vh.f);
  return (((uint32_t)h) << 16) | (uint32_t)l;
}

// ---------------- weight pre-split: f32 -> packed (hi|lo) u32 ----------------
__global__ __launch_bounds__(256)
void convw_kernel(const float* __restrict__ src, uint32_t* __restrict__ dst, int n4)
{
  for (int i = blockIdx.x*256 + threadIdx.x; i < n4; i += gridDim.x*256) {
    const float4 f = ((const float4*)src)[i];
    uint4 o;
    o.x = split_bf(f.x); o.y = split_bf(f.y); o.z = split_bf(f.z); o.w = split_bf(f.w);
    ((uint4*)dst)[i] = o;
  }
}

// ---------------- LayerNorm; OMODE: 0=f32, 1=packed u32, 2=bf16 ushort ----------------
template<int OMODE>
__global__ __launch_bounds__(256)
void ln_kernel(const float* __restrict__ in, const int* __restrict__ ids,
               const float* __restrict__ w, const float* __restrict__ b,
               void* __restrict__ outp)
{
  const int row = blockIdx.x;
  const int t = threadIdx.x;
  const float* px = in + (ids ? (size_t)ids[row] * Dm : (size_t)row * Dm);
  float x0 = px[t], x1 = px[t+256], x2 = px[t+512];
  float s  = x0 + x1 + x2;
  float s2 = x0*x0 + x1*x1 + x2*x2;
  #pragma unroll
  for (int o = 32; o > 0; o >>= 1) { s += __shfl_xor(s, o); s2 += __shfl_xor(s2, o); }
  __shared__ float ls[4], ls2[4];
  if ((t & 63) == 0) { ls[t>>6] = s; ls2[t>>6] = s2; }
  __syncthreads();
  s  = ls[0]+ls[1]+ls[2]+ls[3];
  s2 = ls2[0]+ls2[1]+ls2[2]+ls2[3];
  const float mu  = s * (1.0f/Dm);
  const float var = s2 * (1.0f/Dm) - mu*mu;
  const float rs  = rsqrtf(var + 1e-5f);
  const float v0 = (x0-mu)*rs*w[t]     + b[t];
  const float v1 = (x1-mu)*rs*w[t+256] + b[t+256];
  const float v2 = (x2-mu)*rs*w[t+512] + b[t+512];
  if (OMODE == 0) {
    float* po = (float*)outp + (size_t)row * Dm;
    po[t] = v0; po[t+256] = v1; po[t+512] = v2;
  } else if (OMODE == 1) {
    uint32_t* po = (uint32_t*)outp + (size_t)row * Dm;
    po[t] = split_bf(v0); po[t+256] = split_bf(v1); po[t+512] = split_bf(v2);
  } else {
    unsigned short* po = (unsigned short*)outp + (size_t)row * Dm;
    po[t] = f2bf(v0); po[t+256] = f2bf(v1); po[t+512] = f2bf(v2);
  }
}

// ---------------- RoPE (in-place on q and k) ----------------
__global__ __launch_bounds__(256)
void rope_kernel(float* __restrict__ q, float* __restrict__ k)
{
  const int gid = blockIdx.x * 256 + threadIdx.x;
  if (gid >= Tt * Hh * 32) return;
  const int tkn = gid / (Hh * 32);
  const int r   = gid - tkn * (Hh * 32);
  const int hh  = r >> 5;
  const int d   = r & 31;
  const int s   = tkn & 1023;
  const float freq = 1.0f / powf(10000.0f, (float)d * (1.0f/32.0f));
  const float ang  = (float)s * freq;
  const float c = cosf(ang), sn = sinf(ang);
  const size_t base = (size_t)tkn * Dm + hh * DHd + d;
  float a1 = q[base], a2 = q[base + 32];
  q[base]      = a1*c - a2*sn;
  q[base + 32] = a1*sn + a2*c;
  float b1 = k[base], b2 = k[base + 32];
  k[base]      = b1*c - b2*sn;
  k[base + 32] = b1*sn + b2*c;
}

// ---------------- TTT chunked scan: 4-way e-split; O written packed ----------------
__global__ __launch_bounds__(256)
void ttt_scan_kernel(const float* __restrict__ qin, const float* __restrict__ kk,
                     const float* __restrict__ vv, uint32_t* __restrict__ ob)
{
  const int head = blockIdx.x >> 2;
  const int es   = blockIdx.x & 3;
  const int b  = head / Hh;
  const int hd = head % Hh;
  const int t  = threadIdx.x;
  __shared__ float Wm[64][17];
  __shared__ float kms[16][68];
  __shared__ float qms[16][68];
  __shared__ float Es[16][16];
  __shared__ float Asc[16][16];

  const int e   = t & 15;
  const int m16 = t >> 4;
  const int sr  = t >> 4;
  const int sc  = (t & 15) * 4;

  for (int i = t; i < 64*17; i += 256) ((float*)Wm)[i] = 0.0f;

  const int tb0 = b * 1024;
  const size_t gbase = (size_t)hd * DHd;
  float4 kr = *(const float4*)&kk [(size_t)(tb0+sr)*Dm + gbase + sc];
  float4 qr = *(const float4*)&qin[(size_t)(tb0+sr)*Dm + gbase + sc];
  __syncthreads();

  for (int c = 0; c < 64; ++c) {
    const int tb = tb0 + c*16;
    *(float4*)&kms[sr][sc] = kr;
    *(float4*)&qms[sr][sc] = qr;
    __syncthreads();
    if (c < 63) {
      kr = *(const float4*)&kk [(size_t)(tb+16+sr)*Dm + gbase + sc];
      qr = *(const float4*)&qin[(size_t)(tb+16+sr)*Dm + gbase + sc];
    }
    const float vreg = vv[(size_t)(tb+m16)*Dm + gbase + es*16 + e];
    float aE = -vreg, aO = 0.0f;
    #pragma unroll
    for (int d = 0; d < 64; ++d) {
      const float w_ = Wm[d][e];
      aE += kms[m16][d] * w_;
      aO += qms[m16][d] * w_;
    }
    float aA = 0.0f;
    #pragma unroll
    for (int d = 0; d < 64; ++d) aA += qms[m16][d] * kms[e][d];
    Es[m16][e]  = aE;
    Asc[m16][e] = (e <= m16) ? (-ETA * aA) : 0.0f;
    __syncthreads();
    float acc = aO;
    #pragma unroll
    for (int n = 0; n < 16; ++n) acc += Asc[m16][n] * Es[n][e];
    ob[(size_t)(tb+m16)*Dm + gbase + es*16 + e] = split_bf(acc);
    #pragma unroll
    for (int j = 0; j < 4; ++j) {
      const int d = m16*4 + j;
      float a = 0.0f;
      #pragma unroll
      for (int m = 0; m < 16; ++m) a += kms[m][d] * Es[m][e];
      Wm[d][e] -= ETA * a;
    }
    __syncthreads();
  }
}

// ---------------- split-bf16 MFMA GEMM on PACKED operands, TM x TN tile ----------------
// A[M,K], B[K,N] packed u32 (hi|lo). acc = hi*hi + hi*lo + lo*hi. 4 waves (2x2).
static __device__ __forceinline__ float gelu_f(float x){
  const float u = 0.7978845608028654f * (x + 0.044715f * x*x*x);
  return 0.5f * x * (1.0f + tanhf(u));
}

template<int TM, int TN, bool BIAS, bool GELU_, bool RES, bool PACKOUT>
__global__ __launch_bounds__(256)
void gemm_kernel(const uint32_t* __restrict__ A, const uint32_t* __restrict__ B,
                 const float* __restrict__ bias, const float* __restrict__ res,
                 void* __restrict__ Cp, int M, int N, int K)
{
  constexpr int FM = TM / 32;   // m-frags per wave
  constexpr int FN = TN / 32;   // n-frags per wave
  __shared__ __attribute__((aligned(16))) unsigned short AsH[TM][64];
  __shared__ __attribute__((aligned(16))) unsigned short AsL[TM][64];
  __shared__ __attribute__((aligned(16))) unsigned short BsH[TN][64];
  __shared__ __attribute__((aligned(16))) unsigned short BsL[TN][64];
  const int t    = threadIdx.x;
  const int lane = t & 63;
  const int fr   = lane & 15;
  const int fg   = lane >> 4;
  const int wave = t >> 6;
  const int wm   = (wave >> 1) * (TM/2);
  const int wn   = (wave & 1) * (TN/2);
  const int row0 = blockIdx.y * TM;
  const int n0   = blockIdx.x * TN;

  f32x4 acc[FM][FN];
  #pragma unroll
  for (int i = 0; i < FM; ++i)
    #pragma unroll
    for (int j = 0; j < FN; ++j)
      #pragma unroll
      for (int r = 0; r < 4; ++r) acc[i][j][r] = 0.0f;

  const int acol = (t & 3) * 16;
  const int kk2  = (t >> 6) * 16;

  for (int k0 = 0; k0 < K; k0 += 64) {
    #pragma unroll
    for (int r0 = 0; r0 < TM; r0 += 64) { // stage A rows r0..r0+63
      const int arow = r0 + (t >> 2);
      const uint32_t* src = A + (size_t)(row0 + arow) * K + k0 + acol;
      #pragma unroll
      for (int i = 0; i < 2; ++i) {
        const uint4 p0 = *(const uint4*)(src + i*8);
        const uint4 p1 = *(const uint4*)(src + i*8 + 4);
        ushort8 uh, ul;
        uh[0]=(unsigned short)(p0.x>>16); ul[0]=(unsigned short)p0.x;
        uh[1]=(unsigned short)(p0.y>>16); ul[1]=(unsigned short)p0.y;
        uh[2]=(unsigned short)(p0.z>>16); ul[2]=(unsigned short)p0.z;
        uh[3]=(unsigned short)(p0.w>>16); ul[3]=(unsigned short)p0.w;
        uh[4]=(unsigned short)(p1.x>>16); ul[4]=(unsigned short)p1.x;
        uh[5]=(unsigned short)(p1.y>>16); ul[5]=(unsigned short)p1.y;
        uh[6]=(unsigned short)(p1.z>>16); ul[6]=(unsigned short)p1.z;
        uh[7]=(unsigned short)(p1.w>>16); ul[7]=(unsigned short)p1.w;
        const int byt = (arow*128 + acol*2 + i*16) ^ ((arow & 7) << 4);
        *(ushort8*)((char*)AsH + byt) = uh;
        *(ushort8*)((char*)AsL + byt) = ul;
      }
    }
    #pragma unroll
    for (int nb = 0; nb < TN; nb += 64) { // stage B cols nb..nb+63 (column reads)
      const int bn = nb + (t & 63);
      uint32_t tp[16];
      #pragma unroll
      for (int i = 0; i < 16; ++i)
        tp[i] = B[(size_t)(k0 + kk2 + i) * N + n0 + bn];
      #pragma unroll
      for (int i = 0; i < 2; ++i) {
        ushort8 uh, ul;
        #pragma unroll
        for (int j = 0; j < 8; ++j) {
          const uint32_t p = tp[i*8 + j];
          uh[j] = (unsigned short)(p >> 16);
          ul[j] = (unsigned short)p;
        }
        const int byt = (bn*128 + kk2*2 + i*16) ^ ((bn & 7) << 4);
        *(ushort8*)((char*)BsH + byt) = uh;
        *(ushort8*)((char*)BsL + byt) = ul;
      }
    }
    __syncthreads();
    #pragma unroll
    for (int kh = 0; kh < 2; ++kh) {
      bf16x8 ah[FM], al[FM], bh[FN], bl[FN];
      const int swz = (fr & 7) << 4;
      #pragma unroll
      for (int mt = 0; mt < FM; ++mt) {
        const int byt = ((wm + mt*16 + fr)*128 + kh*64 + fg*16) ^ swz;
        ah[mt] = *(const bf16x8*)((const char*)AsH + byt);
        al[mt] = *(const bf16x8*)((const char*)AsL + byt);
      }
      #pragma unroll
      for (int nt = 0; nt < FN; ++nt) {
        const int byt = ((wn + nt*16 + fr)*128 + kh*64 + fg*16) ^ swz;
        bh[nt] = *(const bf16x8*)((const char*)BsH + byt);
        bl[nt] = *(const bf16x8*)((const char*)BsL + byt);
      }
      #pragma unroll
      for (int mt = 0; mt < FM; ++mt)
        #pragma unroll
        for (int nt = 0; nt < FN; ++nt) {
          acc[mt][nt] = __builtin_amdgcn_mfma_f32_16x16x32_bf16(ah[mt], bh[nt], acc[mt][nt], 0, 0, 0);
          acc[mt][nt] = __builtin_amdgcn_mfma_f32_16x16x32_bf16(ah[mt], bl[nt], acc[mt][nt], 0, 0, 0);
          acc[mt][nt] = __builtin_amdgcn_mfma_f32_16x16x32_bf16(al[mt], bh[nt], acc[mt][nt], 0, 0, 0);
        }
    }
    __syncthreads();
  }

  #pragma unroll
  for (int mt = 0; mt < FM; ++mt) {
    #pragma unroll
    for (int nt = 0; nt < FN; ++nt) {
      const int col = n0 + wn + nt*16 + fr;
      const int rbase = row0 + wm + mt*16 + fg*4;
      const float bcol = BIAS ? bias[col] : 0.0f;
      #pragma unroll
      for (int r = 0; r < 4; ++r) {
        float val = acc[mt][nt][r];
        if (BIAS)  val += bcol;
        if (GELU_) val = gelu_f(val);
        const size_t off = (size_t)(rbase + r) * N + col;
        if (PACKOUT) {
          ((uint32_t*)Cp)[off] = split_bf(val);
        } else {
          if (RES) val += res[off];
          ((float*)Cp)[off] = val;
        }
      }
    }
  }
}

// ---------------- logits GEMM: fragment-linear B panel, no in-loop barriers ----------------
// A = hbf[4096][768] bf16 (L2-resident, read direct from global).
// B = tok_emb rows -> Bp in MFMA-fragment order: chunk (ks,kh,nt), offset lane*16B.
// Block: 32 vocab cols x 4096 rows (16 m-tiles of 256). 512 thr, 8 waves, 48 KB LDS.
__global__ __launch_bounds__(512)
void logits_kernel(const unsigned short* __restrict__ hbf, const float* __restrict__ tok,
                   float* __restrict__ C)
{
  __shared__ unsigned short Bp[48*512];   // 48 chunks x 64 lanes x 16B = 48 KB
  const int t  = threadIdx.x;
  const int n0 = blockIdx.x * 32;

  for (int s = t; s < 3072; s += 512) {   // fill B panel in fragment order
    const int chunk = s >> 6, lne = s & 63;
    const int ffr = lne & 15, ffg = lne >> 4;
    const int ks = chunk >> 2, rr = chunk & 3;
    const int kh = rr >> 1, nt = rr & 1;
    const int row = n0 + nt*16 + ffr;
    const int col = ks*64 + kh*32 + ffg*8;
    ushort8 u;
    if (row < Vv) {
      const float4 f0 = *(const float4*)&tok[(size_t)row*Dm + col];
      const float4 f1 = *(const float4*)&tok[(size_t)row*Dm + col + 4];
      u[0]=f2bf(f0.x); u[1]=f2bf(f0.y); u[2]=f2bf(f0.z); u[3]=f2bf(f0.w);
      u[4]=f2bf(f1.x); u[5]=f2bf(f1.y); u[6]=f2bf(f1.z); u[7]=f2bf(f1.w);
    } else {
      #pragma unroll
      for (int j = 0; j < 8; ++j) u[j] = 0;
    }
    *(ushort8*)&Bp[s*8] = u;
  }
  __syncthreads();

  const int lane = t & 63, fr = lane & 15, fg = lane >> 4;
  const int wave = t >> 6;

  for (int mi = 0; mi < 16; ++mi) {
    const int row0 = mi*256 + wave*32;
    f32x4 acc[2][2];
    #pragma unroll
    for (int i = 0; i < 2; ++i)
      #pragma unroll
      for (int j = 0; j < 2; ++j)
        #pragma unroll
        for (int r = 0; r < 4; ++r) acc[i][j][r] = 0.0f;

    #pragma unroll
    for (int ks = 0; ks < 12; ++ks) {
      #pragma unroll
      for (int kh = 0; kh < 2; ++kh) {
        bf16x8 af[2], bfr[2];
        #pragma unroll
        for (int mt = 0; mt < 2; ++mt)
          af[mt] = *(const bf16x8*)&hbf[(size_t)(row0 + mt*16 + fr)*Dm + ks*64 + kh*32 + fg*8];
        #pragma unroll
        for (int nt = 0; nt < 2; ++nt)
          bfr[nt] = *(const bf16x8*)&Bp[((((ks*2 + kh)*2 + nt)*64) + lane)*8];
        #pragma unroll
        for (int mt = 0; mt < 2; ++mt)
          #pragma unroll
          for (int nt = 0; nt < 2; ++nt)
            acc[mt][nt] = __builtin_amdgcn_mfma_f32_16x16x32_bf16(af[mt], bfr[nt], acc[mt][nt], 0, 0, 0);
      }
    }
    #pragma unroll
    for (int mt = 0; mt < 2; ++mt) {
      #pragma unroll
      for (int nt = 0; nt < 2; ++nt) {
        const int col = n0 + nt*16 + fr;
        if (col < Vv) {
          const int rbase = row0 + mt*16 + fg*4;
          #pragma unroll
          for (int r = 0; r < 4; ++r)
            C[(size_t)(rbase + r) * Vv + col] = acc[mt][nt][r];
        }
      }
    }
  }
}

// ---------------- host-side orchestration ----------------
extern "C" void kernel_launch(void* const* d_in, const int* in_sizes, int n_in,
                              void* d_out, int out_size, void* d_ws, size_t ws_size,
                              hipStream_t stream)
{
  const int*   ids = (const int*)  d_in[0];
  const float* tok = (const float*)d_in[1];
  const float* ew  = (const float*)d_in[2];
  const float* eb  = (const float*)d_in[3];
  const float* wq  = (const float*)d_in[4];
  const float* wk  = (const float*)d_in[5];
  const float* wv  = (const float*)d_in[6];
  const float* wo  = (const float*)d_in[7];
  const float* n1w = (const float*)d_in[8];
  const float* n1b = (const float*)d_in[9];
  const float* n2w = (const float*)d_in[10];
  const float* n2b = (const float*)d_in[11];
  const float* m1w = (const float*)d_in[12];
  const float* m1b = (const float*)d_in[13];
  const float* m2w = (const float*)d_in[14];
  const float* m2b = (const float*)d_in[15];
  const float* onw = (const float*)d_in[16];
  const float* onb = (const float*)d_in[17];

  // ws: x (f32 residual), h (packed u32 / bf16 ushort, reused)
  float* x = (float*)d_ws;
  float* h = x + (size_t)Tt * Dm;
  float* out = (float*)d_out;
  // d_out scratch (all dead before logits writes C):
  uint32_t* g  = (uint32_t*)d_out;              // packed g [4096][3072]
  float* q  = out + (size_t)(1u << 24);
  float* k  = q   + (size_t)(1u << 22);
  float* v  = k   + (size_t)(1u << 22);
  uint32_t* ob = (uint32_t*)(v + (size_t)(1u << 22));
  uint32_t* wpk = (uint32_t*)d_out + 40000000u; // packed weights, 85M u32
  const size_t SQQ = (size_t)Ll * Dm * Dm;      // 7,077,888
  const size_t SMM = (size_t)Ll * Dm * Ff;      // 28,311,552
  uint32_t* wq_pk = wpk;
  uint32_t* wk_pk = wq_pk + SQQ;
  uint32_t* wv_pk = wk_pk + SQQ;
  uint32_t* wo_pk = wv_pk + SQQ;
  uint32_t* m1_pk = wo_pk + SQQ;
  uint32_t* m2_pk = m1_pk + SMM;

  convw_kernel<<<1024, 256, 0, stream>>>(wq, wq_pk, (int)(SQQ/4));
  convw_kernel<<<1024, 256, 0, stream>>>(wk, wk_pk, (int)(SQQ/4));
  convw_kernel<<<1024, 256, 0, stream>>>(wv, wv_pk, (int)(SQQ/4));
  convw_kernel<<<1024, 256, 0, stream>>>(wo, wo_pk, (int)(SQQ/4));
  convw_kernel<<<2048, 256, 0, stream>>>(m1w, m1_pk, (int)(SMM/4));
  convw_kernel<<<2048, 256, 0, stream>>>(m2w, m2_pk, (int)(SMM/4));

  ln_kernel<0><<<Tt, 256, 0, stream>>>(tok, ids, ew, eb, x);

  for (int l = 0; l < Ll; ++l) {
    ln_kernel<1><<<Tt, 256, 0, stream>>>(x, nullptr, n1w + l*Dm, n1b + l*Dm, h);
    gemm_kernel<64,64,false,false,false,false><<<dim3(12,64), 256, 0, stream>>>(
        (const uint32_t*)h, wq_pk + (size_t)l*Dm*Dm, nullptr, nullptr, q, Tt, Dm, Dm);
    gemm_kernel<64,64,false,false,false,false><<<dim3(12,64), 256, 0, stream>>>(
        (const uint32_t*)h, wk_pk + (size_t)l*Dm*Dm, nullptr, nullptr, k, Tt, Dm, Dm);
    gemm_kernel<64,64,false,false,false,false><<<dim3(12,64), 256, 0, stream>>>(
        (const uint32_t*)h, wv_pk + (size_t)l*Dm*Dm, nullptr, nullptr, v, Tt, Dm, Dm);
    rope_kernel<<<6144, 256, 0, stream>>>(q, k);
    ttt_scan_kernel<<<192, 256, 0, stream>>>(q, k, v, ob);
    gemm_kernel<64,64,false,false,true,false><<<dim3(12,64), 256, 0, stream>>>(
        ob, wo_pk + (size_t)l*Dm*Dm, nullptr, x, x, Tt, Dm, Dm);
    ln_kernel<1><<<Tt, 256, 0, stream>>>(x, nullptr, n2w + l*Dm, n2b + l*Dm, h);
    gemm_kernel<128,128,true,true,false,true><<<dim3(24,32), 256, 0, stream>>>(
        (const uint32_t*)h, m1_pk + (size_t)l*Dm*Ff, m1b + (size_t)l*Ff, nullptr, g, Tt, Ff, Dm);
    gemm_kernel<64,64,true,false,true,false><<<dim3(12,64), 256, 0, stream>>>(
        g, m2_pk + (size_t)l*Ff*Dm, m2b + (size_t)l*Dm, x, x, Tt, Dm, Ff);
  }

  ln_kernel<2><<<Tt, 256, 0, stream>>>(x, nullptr, onw, onb, h);
  logits_kernel<<<dim3(1571, 1), 512, 0, stream>>>((const unsigned short*)h, tok, out);
}

// Round 7
// 6043.782 us; speedup vs baseline: 1.1757x; 1.1757x over previous
//
#include <hip/hip_runtime.h>
#include <cstdint>
#include <cstddef>

#define Dm 768
#define Hh 12
#define DHd 64
#define Ll 12
#define Vv 50257
#define Tt 4096
#define Ff 3072
#define ETA (1.0f/16.0f)

typedef __attribute__((ext_vector_type(8))) short bf16x8;
typedef __attribute__((ext_vector_type(8))) unsigned short ushort8;
typedef __attribute__((ext_vector_type(4))) float f32x4;

static __device__ __forceinline__ unsigned short f2bf(float f){
  union { float f; unsigned int u; } v; v.f = f;
  unsigned int r = v.u + 0x7fffu + ((v.u >> 16) & 1u);
  return (unsigned short)(r >> 16);
}
// cheap round-half-up bf16 (2 VALU): fine for |x| << inf
static __device__ __forceinline__ unsigned short f2bf_rhu(float f){
  union { float f; unsigned int u; } v; v.f = f;
  return (unsigned short)((v.u + 0x8000u) >> 16);
}
// returns (hi<<16)|lo : hi=bf16(f), lo=bf16(f - hi)
static __device__ __forceinline__ uint32_t split_bf(float f){
  const unsigned short h = f2bf(f);
  union { uint32_t u; float f; } vh; vh.u = ((uint32_t)h) << 16;
  const unsigned short l = f2bf(f - vh.f);
  return (((uint32_t)h) << 16) | (uint32_t)l;
}

// ---------------- weight pre-split: f32 -> packed (hi|lo) u32 ----------------
__global__ __launch_bounds__(256)
void convw_kernel(const float* __restrict__ src, uint32_t* __restrict__ dst, int n4)
{
  for (int i = blockIdx.x*256 + threadIdx.x; i < n4; i += gridDim.x*256) {
    const float4 f = ((const float4*)src)[i];
    uint4 o;
    o.x = split_bf(f.x); o.y = split_bf(f.y); o.z = split_bf(f.z); o.w = split_bf(f.w);
    ((uint4*)dst)[i] = o;
  }
}

// ---------------- LayerNorm; OMODE: 0=f32, 1=packed u32, 2=bf16 ushort ----------------
template<int OMODE>
__global__ __launch_bounds__(256)
void ln_kernel(const float* __restrict__ in, const int* __restrict__ ids,
               const float* __restrict__ w, const float* __restrict__ b,
               void* __restrict__ outp)
{
  const int row = blockIdx.x;
  const int t = threadIdx.x;
  const float* px = in + (ids ? (size_t)ids[row] * Dm : (size_t)row * Dm);
  float x0 = px[t], x1 = px[t+256], x2 = px[t+512];
  float s  = x0 + x1 + x2;
  float s2 = x0*x0 + x1*x1 + x2*x2;
  #pragma unroll
  for (int o = 32; o > 0; o >>= 1) { s += __shfl_xor(s, o); s2 += __shfl_xor(s2, o); }
  __shared__ float ls[4], ls2[4];
  if ((t & 63) == 0) { ls[t>>6] = s; ls2[t>>6] = s2; }
  __syncthreads();
  s  = ls[0]+ls[1]+ls[2]+ls[3];
  s2 = ls2[0]+ls2[1]+ls2[2]+ls2[3];
  const float mu  = s * (1.0f/Dm);
  const float var = s2 * (1.0f/Dm) - mu*mu;
  const float rs  = rsqrtf(var + 1e-5f);
  const float v0 = (x0-mu)*rs*w[t]     + b[t];
  const float v1 = (x1-mu)*rs*w[t+256] + b[t+256];
  const float v2 = (x2-mu)*rs*w[t+512] + b[t+512];
  if (OMODE == 0) {
    float* po = (float*)outp + (size_t)row * Dm;
    po[t] = v0; po[t+256] = v1; po[t+512] = v2;
  } else if (OMODE == 1) {
    uint32_t* po = (uint32_t*)outp + (size_t)row * Dm;
    po[t] = split_bf(v0); po[t+256] = split_bf(v1); po[t+512] = split_bf(v2);
  } else {
    unsigned short* po = (unsigned short*)outp + (size_t)row * Dm;
    po[t] = f2bf(v0); po[t+256] = f2bf(v1); po[t+512] = f2bf(v2);
  }
}

// ---------------- RoPE (in-place on q and k) ----------------
__global__ __launch_bounds__(256)
void rope_kernel(float* __restrict__ q, float* __restrict__ k)
{
  const int gid = blockIdx.x * 256 + threadIdx.x;
  if (gid >= Tt * Hh * 32) return;
  const int tkn = gid / (Hh * 32);
  const int r   = gid - tkn * (Hh * 32);
  const int hh  = r >> 5;
  const int d   = r & 31;
  const int s   = tkn & 1023;
  const float freq = 1.0f / powf(10000.0f, (float)d * (1.0f/32.0f));
  const float ang  = (float)s * freq;
  const float c = cosf(ang), sn = sinf(ang);
  const size_t base = (size_t)tkn * Dm + hh * DHd + d;
  float a1 = q[base], a2 = q[base + 32];
  q[base]      = a1*c - a2*sn;
  q[base + 32] = a1*sn + a2*c;
  float b1 = k[base], b2 = k[base + 32];
  k[base]      = b1*c - b2*sn;
  k[base + 32] = b1*sn + b2*c;
}

// ---------------- TTT chunked scan: 4-way e-split; O written packed ----------------
__global__ __launch_bounds__(256)
void ttt_scan_kernel(const float* __restrict__ qin, const float* __restrict__ kk,
                     const float* __restrict__ vv, uint32_t* __restrict__ ob)
{
  const int head = blockIdx.x >> 2;
  const int es   = blockIdx.x & 3;
  const int b  = head / Hh;
  const int hd = head % Hh;
  const int t  = threadIdx.x;
  __shared__ float Wm[64][17];
  __shared__ float kms[16][68];
  __shared__ float qms[16][68];
  __shared__ float Es[16][16];
  __shared__ float Asc[16][16];

  const int e   = t & 15;
  const int m16 = t >> 4;
  const int sr  = t >> 4;
  const int sc  = (t & 15) * 4;

  for (int i = t; i < 64*17; i += 256) ((float*)Wm)[i] = 0.0f;

  const int tb0 = b * 1024;
  const size_t gbase = (size_t)hd * DHd;
  float4 kr = *(const float4*)&kk [(size_t)(tb0+sr)*Dm + gbase + sc];
  float4 qr = *(const float4*)&qin[(size_t)(tb0+sr)*Dm + gbase + sc];
  __syncthreads();

  for (int c = 0; c < 64; ++c) {
    const int tb = tb0 + c*16;
    *(float4*)&kms[sr][sc] = kr;
    *(float4*)&qms[sr][sc] = qr;
    __syncthreads();
    if (c < 63) {
      kr = *(const float4*)&kk [(size_t)(tb+16+sr)*Dm + gbase + sc];
      qr = *(const float4*)&qin[(size_t)(tb+16+sr)*Dm + gbase + sc];
    }
    const float vreg = vv[(size_t)(tb+m16)*Dm + gbase + es*16 + e];
    float aE = -vreg, aO = 0.0f;
    #pragma unroll
    for (int d = 0; d < 64; ++d) {
      const float w_ = Wm[d][e];
      aE += kms[m16][d] * w_;
      aO += qms[m16][d] * w_;
    }
    float aA = 0.0f;
    #pragma unroll
    for (int d = 0; d < 64; ++d) aA += qms[m16][d] * kms[e][d];
    Es[m16][e]  = aE;
    Asc[m16][e] = (e <= m16) ? (-ETA * aA) : 0.0f;
    __syncthreads();
    float acc = aO;
    #pragma unroll
    for (int n = 0; n < 16; ++n) acc += Asc[m16][n] * Es[n][e];
    ob[(size_t)(tb+m16)*Dm + gbase + es*16 + e] = split_bf(acc);
    #pragma unroll
    for (int j = 0; j < 4; ++j) {
      const int d = m16*4 + j;
      float a = 0.0f;
      #pragma unroll
      for (int m = 0; m < 16; ++m) a += kms[m][d] * Es[m][e];
      Wm[d][e] -= ETA * a;
    }
    __syncthreads();
  }
}

// ---------------- split-bf16 MFMA GEMM on PACKED operands, TM x TN tile ----------------
static __device__ __forceinline__ float gelu_f(float x){
  const float u = 0.7978845608028654f * (x + 0.044715f * x*x*x);
  return 0.5f * x * (1.0f + tanhf(u));
}

template<int TM, int TN, bool BIAS, bool GELU_, bool RES, bool PACKOUT>
__global__ __launch_bounds__(256)
void gemm_kernel(const uint32_t* __restrict__ A, const uint32_t* __restrict__ B,
                 const float* __restrict__ bias, const float* __restrict__ res,
                 void* __restrict__ Cp, int M, int N, int K)
{
  constexpr int FM = TM / 32;
  constexpr int FN = TN / 32;
  __shared__ __attribute__((aligned(16))) unsigned short AsH[TM][64];
  __shared__ __attribute__((aligned(16))) unsigned short AsL[TM][64];
  __shared__ __attribute__((aligned(16))) unsigned short BsH[TN][64];
  __shared__ __attribute__((aligned(16))) unsigned short BsL[TN][64];
  const int t    = threadIdx.x;
  const int lane = t & 63;
  const int fr   = lane & 15;
  const int fg   = lane >> 4;
  const int wave = t >> 6;
  const int wm   = (wave >> 1) * (TM/2);
  const int wn   = (wave & 1) * (TN/2);
  const int row0 = blockIdx.y * TM;
  const int n0   = blockIdx.x * TN;

  f32x4 acc[FM][FN];
  #pragma unroll
  for (int i = 0; i < FM; ++i)
    #pragma unroll
    for (int j = 0; j < FN; ++j)
      #pragma unroll
      for (int r = 0; r < 4; ++r) acc[i][j][r] = 0.0f;

  const int acol = (t & 3) * 16;
  const int kk2  = (t >> 6) * 16;

  for (int k0 = 0; k0 < K; k0 += 64) {
    #pragma unroll
    for (int r0 = 0; r0 < TM; r0 += 64) {
      const int arow = r0 + (t >> 2);
      const uint32_t* src = A + (size_t)(row0 + arow) * K + k0 + acol;
      #pragma unroll
      for (int i = 0; i < 2; ++i) {
        const uint4 p0 = *(const uint4*)(src + i*8);
        const uint4 p1 = *(const uint4*)(src + i*8 + 4);
        ushort8 uh, ul;
        uh[0]=(unsigned short)(p0.x>>16); ul[0]=(unsigned short)p0.x;
        uh[1]=(unsigned short)(p0.y>>16); ul[1]=(unsigned short)p0.y;
        uh[2]=(unsigned short)(p0.z>>16); ul[2]=(unsigned short)p0.z;
        uh[3]=(unsigned short)(p0.w>>16); ul[3]=(unsigned short)p0.w;
        uh[4]=(unsigned short)(p1.x>>16); ul[4]=(unsigned short)p1.x;
        uh[5]=(unsigned short)(p1.y>>16); ul[5]=(unsigned short)p1.y;
        uh[6]=(unsigned short)(p1.z>>16); ul[6]=(unsigned short)p1.z;
        uh[7]=(unsigned short)(p1.w>>16); ul[7]=(unsigned short)p1.w;
        const int byt = (arow*128 + acol*2 + i*16) ^ ((arow & 7) << 4);
        *(ushort8*)((char*)AsH + byt) = uh;
        *(ushort8*)((char*)AsL + byt) = ul;
      }
    }
    #pragma unroll
    for (int nb = 0; nb < TN; nb += 64) {
      const int bn = nb + (t & 63);
      uint32_t tp[16];
      #pragma unroll
      for (int i = 0; i < 16; ++i)
        tp[i] = B[(size_t)(k0 + kk2 + i) * N + n0 + bn];
      #pragma unroll
      for (int i = 0; i < 2; ++i) {
        ushort8 uh, ul;
        #pragma unroll
        for (int j = 0; j < 8; ++j) {
          const uint32_t p = tp[i*8 + j];
          uh[j] = (unsigned short)(p >> 16);
          ul[j] = (unsigned short)p;
        }
        const int byt = (bn*128 + kk2*2 + i*16) ^ ((bn & 7) << 4);
        *(ushort8*)((char*)BsH + byt) = uh;
        *(ushort8*)((char*)BsL + byt) = ul;
      }
    }
    __syncthreads();
    #pragma unroll
    for (int kh = 0; kh < 2; ++kh) {
      bf16x8 ah[FM], al[FM], bh[FN], bl[FN];
      const int swz = (fr & 7) << 4;
      #pragma unroll
      for (int mt = 0; mt < FM; ++mt) {
        const int byt = ((wm + mt*16 + fr)*128 + kh*64 + fg*16) ^ swz;
        ah[mt] = *(const bf16x8*)((const char*)AsH + byt);
        al[mt] = *(const bf16x8*)((const char*)AsL + byt);
      }
      #pragma unroll
      for (int nt = 0; nt < FN; ++nt) {
        const int byt = ((wn + nt*16 + fr)*128 + kh*64 + fg*16) ^ swz;
        bh[nt] = *(const bf16x8*)((const char*)BsH + byt);
        bl[nt] = *(const bf16x8*)((const char*)BsL + byt);
      }
      #pragma unroll
      for (int mt = 0; mt < FM; ++mt)
        #pragma unroll
        for (int nt = 0; nt < FN; ++nt) {
          acc[mt][nt] = __builtin_amdgcn_mfma_f32_16x16x32_bf16(ah[mt], bh[nt], acc[mt][nt], 0, 0, 0);
          acc[mt][nt] = __builtin_amdgcn_mfma_f32_16x16x32_bf16(ah[mt], bl[nt], acc[mt][nt], 0, 0, 0);
          acc[mt][nt] = __builtin_amdgcn_mfma_f32_16x16x32_bf16(al[mt], bh[nt], acc[mt][nt], 0, 0, 0);
        }
    }
    __syncthreads();
  }

  #pragma unroll
  for (int mt = 0; mt < FM; ++mt) {
    #pragma unroll
    for (int nt = 0; nt < FN; ++nt) {
      const int col = n0 + wn + nt*16 + fr;
      const int rbase = row0 + wm + mt*16 + fg*4;
      const float bcol = BIAS ? bias[col] : 0.0f;
      #pragma unroll
      for (int r = 0; r < 4; ++r) {
        float val = acc[mt][nt][r];
        if (BIAS)  val += bcol;
        if (GELU_) val = gelu_f(val);
        const size_t off = (size_t)(rbase + r) * N + col;
        if (PACKOUT) {
          ((uint32_t*)Cp)[off] = split_bf(val);
        } else {
          if (RES) val += res[off];
          ((float*)Cp)[off] = val;
        }
      }
    }
  }
}

// ---------------- logits GEMM v3: 128x128 2-phase tile, C = hbf @ tok^T ----------------
// A = hbf[4096][768] bf16. B rows from tok f32, converted in-staging (round-half-up).
// Grid linear 393*32 (n-outer, m-inner) + bijective XCD chunk swizzle (12576 % 8 == 0).
__global__ __launch_bounds__(256)
void logits_kernel(const unsigned short* __restrict__ hbf, const float* __restrict__ tok,
                   float* __restrict__ C)
{
  __shared__ __attribute__((aligned(16))) unsigned short As[128*64];
  __shared__ __attribute__((aligned(16))) unsigned short Bs[128*64];
  int bid = blockIdx.x;
  bid = (bid & 7) * 1572 + (bid >> 3);       // XCD swizzle: 12576/8 = 1572
  const int n0   = (bid >> 5) * 128;         // 393 n-groups (outer)
  const int row0 = (bid & 31) * 128;         // 32 m-tiles (inner, share B panel)

  const int t    = threadIdx.x;
  const int lane = t & 63;
  const int fr   = lane & 15;
  const int fg   = lane >> 4;
  const int wave = t >> 6;
  const int wm   = (wave >> 1) * 64;
  const int wn   = (wave & 1) * 64;

  const int arow = t >> 1;              // 0..127
  const int ach  = (t & 1) * 32;        // col half

  f32x4 acc[4][4];
  #pragma unroll
  for (int i = 0; i < 4; ++i)
    #pragma unroll
    for (int j = 0; j < 4; ++j)
      #pragma unroll
      for (int r = 0; r < 4; ++r) acc[i][j][r] = 0.0f;

  for (int ks = 0; ks < 12; ++ks) {
    { // stage A: 128 rows x 64 cols bf16 (direct copy)
      const unsigned short* src = &hbf[(size_t)arow * Dm + ks*64 + ach] + (size_t)row0 * Dm;
      #pragma unroll
      for (int i = 0; i < 4; ++i) {
        const ushort8 u = *(const ushort8*)(src + i*8);
        const int byt = (arow*128 + (ach + i*8)*2) ^ ((arow & 7) << 4);
        *(ushort8*)((char*)As + byt) = u;
      }
    }
    { // stage B: 128 tok-rows x 64 cols, f32 -> bf16 round-half-up
      const int brow = n0 + arow;
      if (brow < Vv) {
        const float* src = &tok[(size_t)brow * Dm + ks*64 + ach];
        #pragma unroll
        for (int i = 0; i < 4; ++i) {
          const float4 f0 = *(const float4*)(src + i*8);
          const float4 f1 = *(const float4*)(src + i*8 + 4);
          ushort8 u;
          u[0]=f2bf_rhu(f0.x); u[1]=f2bf_rhu(f0.y); u[2]=f2bf_rhu(f0.z); u[3]=f2bf_rhu(f0.w);
          u[4]=f2bf_rhu(f1.x); u[5]=f2bf_rhu(f1.y); u[6]=f2bf_rhu(f1.z); u[7]=f2bf_rhu(f1.w);
          const int byt = (arow*128 + (ach + i*8)*2) ^ ((arow & 7) << 4);
          *(ushort8*)((char*)Bs + byt) = u;
        }
      } else {
        ushort8 z;
        #pragma unroll
        for (int j = 0; j < 8; ++j) z[j] = 0;
        #pragma unroll
        for (int i = 0; i < 4; ++i) {
          const int byt = (arow*128 + (ach + i*8)*2) ^ ((arow & 7) << 4);
          *(ushort8*)((char*)Bs + byt) = z;
        }
      }
    }
    __syncthreads();
    #pragma unroll
    for (int kh = 0; kh < 2; ++kh) {
      bf16x8 af[4], bfr[4];
      const int swz = (fr & 7) << 4;
      #pragma unroll
      for (int mt = 0; mt < 4; ++mt)
        af[mt] = *(const bf16x8*)((const char*)As + (((wm + mt*16 + fr)*128 + kh*64 + fg*16) ^ swz));
      #pragma unroll
      for (int nt = 0; nt < 4; ++nt)
        bfr[nt] = *(const bf16x8*)((const char*)Bs + (((wn + nt*16 + fr)*128 + kh*64 + fg*16) ^ swz));
      #pragma unroll
      for (int mt = 0; mt < 4; ++mt)
        #pragma unroll
        for (int nt = 0; nt < 4; ++nt)
          acc[mt][nt] = __builtin_amdgcn_mfma_f32_16x16x32_bf16(af[mt], bfr[nt], acc[mt][nt], 0, 0, 0);
    }
    __syncthreads();
  }

  #pragma unroll
  for (int mt = 0; mt < 4; ++mt) {
    #pragma unroll
    for (int nt = 0; nt < 4; ++nt) {
      const int col = n0 + wn + nt*16 + fr;
      if (col < Vv) {
        const int rbase = row0 + wm + mt*16 + fg*4;
        #pragma unroll
        for (int r = 0; r < 4; ++r)
          C[(size_t)(rbase + r) * Vv + col] = acc[mt][nt][r];
      }
    }
  }
}

// ---------------- host-side orchestration ----------------
extern "C" void kernel_launch(void* const* d_in, const int* in_sizes, int n_in,
                              void* d_out, int out_size, void* d_ws, size_t ws_size,
                              hipStream_t stream)
{
  const int*   ids = (const int*)  d_in[0];
  const float* tok = (const float*)d_in[1];
  const float* ew  = (const float*)d_in[2];
  const float* eb  = (const float*)d_in[3];
  const float* wq  = (const float*)d_in[4];
  const float* wk  = (const float*)d_in[5];
  const float* wv  = (const float*)d_in[6];
  const float* wo  = (const float*)d_in[7];
  const float* n1w = (const float*)d_in[8];
  const float* n1b = (const float*)d_in[9];
  const float* n2w = (const float*)d_in[10];
  const float* n2b = (const float*)d_in[11];
  const float* m1w = (const float*)d_in[12];
  const float* m1b = (const float*)d_in[13];
  const float* m2w = (const float*)d_in[14];
  const float* m2b = (const float*)d_in[15];
  const float* onw = (const float*)d_in[16];
  const float* onb = (const float*)d_in[17];

  float* x = (float*)d_ws;
  float* h = x + (size_t)Tt * Dm;
  float* out = (float*)d_out;
  uint32_t* g  = (uint32_t*)d_out;
  float* q  = out + (size_t)(1u << 24);
  float* k  = q   + (size_t)(1u << 22);
  float* v  = k   + (size_t)(1u << 22);
  uint32_t* ob = (uint32_t*)(v + (size_t)(1u << 22));
  uint32_t* wpk = (uint32_t*)d_out + 40000000u;
  const size_t SQQ = (size_t)Ll * Dm * Dm;
  const size_t SMM = (size_t)Ll * Dm * Ff;
  uint32_t* wq_pk = wpk;
  uint32_t* wk_pk = wq_pk + SQQ;
  uint32_t* wv_pk = wk_pk + SQQ;
  uint32_t* wo_pk = wv_pk + SQQ;
  uint32_t* m1_pk = wo_pk + SQQ;
  uint32_t* m2_pk = m1_pk + SMM;

  convw_kernel<<<1024, 256, 0, stream>>>(wq, wq_pk, (int)(SQQ/4));
  convw_kernel<<<1024, 256, 0, stream>>>(wk, wk_pk, (int)(SQQ/4));
  convw_kernel<<<1024, 256, 0, stream>>>(wv, wv_pk, (int)(SQQ/4));
  convw_kernel<<<1024, 256, 0, stream>>>(wo, wo_pk, (int)(SQQ/4));
  convw_kernel<<<2048, 256, 0, stream>>>(m1w, m1_pk, (int)(SMM/4));
  convw_kernel<<<2048, 256, 0, stream>>>(m2w, m2_pk, (int)(SMM/4));

  ln_kernel<0><<<Tt, 256, 0, stream>>>(tok, ids, ew, eb, x);

  for (int l = 0; l < Ll; ++l) {
    ln_kernel<1><<<Tt, 256, 0, stream>>>(x, nullptr, n1w + l*Dm, n1b + l*Dm, h);
    gemm_kernel<64,64,false,false,false,false><<<dim3(12,64), 256, 0, stream>>>(
        (const uint32_t*)h, wq_pk + (size_t)l*Dm*Dm, nullptr, nullptr, q, Tt, Dm, Dm);
    gemm_kernel<64,64,false,false,false,false><<<dim3(12,64), 256, 0, stream>>>(
        (const uint32_t*)h, wk_pk + (size_t)l*Dm*Dm, nullptr, nullptr, k, Tt, Dm, Dm);
    gemm_kernel<64,64,false,false,false,false><<<dim3(12,64), 256, 0, stream>>>(
        (const uint32_t*)h, wv_pk + (size_t)l*Dm*Dm, nullptr, nullptr, v, Tt, Dm, Dm);
    rope_kernel<<<6144, 256, 0, stream>>>(q, k);
    ttt_scan_kernel<<<192, 256, 0, stream>>>(q, k, v, ob);
    gemm_kernel<64,64,false,false,true,false><<<dim3(12,64), 256, 0, stream>>>(
        ob, wo_pk + (size_t)l*Dm*Dm, nullptr, x, x, Tt, Dm, Dm);
    ln_kernel<1><<<Tt, 256, 0, stream>>>(x, nullptr, n2w + l*Dm, n2b + l*Dm, h);
    gemm_kernel<128,128,true,true,false,true><<<dim3(24,32), 256, 0, stream>>>(
        (const uint32_t*)h, m1_pk + (size_t)l*Dm*Ff, m1b + (size_t)l*Ff, nullptr, g, Tt, Ff, Dm);
    gemm_kernel<64,64,true,false,true,false><<<dim3(12,64), 256, 0, stream>>>(
        g, m2_pk + (size_t)l*Ff*Dm, m2b + (size_t)l*Dm, x, x, Tt, Dm, Ff);
  }

  ln_kernel<2><<<Tt, 256, 0, stream>>>(x, nullptr, onw, onb, h);
  logits_kernel<<<dim3(12576, 1), 256, 0, stream>>>((const unsigned short*)h, tok, out);
}

// Round 8
// 5693.068 us; speedup vs baseline: 1.2481x; 1.0616x over previous
//
#include <hip/hip_runtime.h>
#include <cstdint>
#include <cstddef>

#define Dm 768
#define Hh 12
#define DHd 64
#define Ll 12
#define Vv 50257
#define Tt 4096
#define Ff 3072
#define QS 2304           // fused qkv row stride
#define ETA (1.0f/16.0f)

typedef __attribute__((ext_vector_type(8))) short bf16x8;
typedef __attribute__((ext_vector_type(8))) unsigned short ushort8;
typedef __attribute__((ext_vector_type(4))) float f32x4;

static __device__ __forceinline__ unsigned short f2bf(float f){
  union { float f; unsigned int u; } v; v.f = f;
  unsigned int r = v.u + 0x7fffu + ((v.u >> 16) & 1u);
  return (unsigned short)(r >> 16);
}
static __device__ __forceinline__ unsigned short f2bf_rhu(float f){
  union { float f; unsigned int u; } v; v.f = f;
  return (unsigned short)((v.u + 0x8000u) >> 16);
}
// returns (hi<<16)|lo : hi=bf16(f), lo=bf16(f - hi)
static __device__ __forceinline__ uint32_t split_bf(float f){
  const unsigned short h = f2bf(f);
  union { uint32_t u; float f; } vh; vh.u = ((uint32_t)h) << 16;
  const unsigned short l = f2bf(f - vh.f);
  return (((uint32_t)h) << 16) | (uint32_t)l;
}

// ---------------- weight pre-split with column remap: f32[rows][ncs] -> packed u32[rows][ncd] at +coff ----------------
__global__ __launch_bounds__(256)
void convw_kernel(const float* __restrict__ src, uint32_t* __restrict__ dst,
                  int n4, int ncs, int ncd, int coff)
{
  for (int i = blockIdx.x*256 + threadIdx.x; i < n4; i += gridDim.x*256) {
    const float4 f = ((const float4*)src)[i];
    uint4 o;
    o.x = split_bf(f.x); o.y = split_bf(f.y); o.z = split_bf(f.z); o.w = split_bf(f.w);
    const int idx4 = i * 4;
    const int row  = idx4 / ncs;
    const int c    = idx4 - row * ncs;
    *(uint4*)&dst[(size_t)row * ncd + coff + c] = o;
  }
}

// ---------------- tok f32 -> bf16 (for logits B) ----------------
__global__ __launch_bounds__(256)
void convtok_kernel(const float* __restrict__ src, unsigned short* __restrict__ dst, int n8)
{
  for (int i = blockIdx.x*256 + threadIdx.x; i < n8; i += gridDim.x*256) {
    const float4 f0 = ((const float4*)src)[i*2];
    const float4 f1 = ((const float4*)src)[i*2+1];
    ushort8 u;
    u[0]=f2bf(f0.x); u[1]=f2bf(f0.y); u[2]=f2bf(f0.z); u[3]=f2bf(f0.w);
    u[4]=f2bf(f1.x); u[5]=f2bf(f1.y); u[6]=f2bf(f1.z); u[7]=f2bf(f1.w);
    *(ushort8*)&dst[i*8] = u;
  }
}

// ---------------- LayerNorm; OMODE: 0=f32, 1=packed u32, 2=bf16 ushort ----------------
template<int OMODE>
__global__ __launch_bounds__(256)
void ln_kernel(const float* __restrict__ in, const int* __restrict__ ids,
               const float* __restrict__ w, const float* __restrict__ b,
               void* __restrict__ outp)
{
  const int row = blockIdx.x;
  const int t = threadIdx.x;
  const float* px = in + (ids ? (size_t)ids[row] * Dm : (size_t)row * Dm);
  float x0 = px[t], x1 = px[t+256], x2 = px[t+512];
  float s  = x0 + x1 + x2;
  float s2 = x0*x0 + x1*x1 + x2*x2;
  #pragma unroll
  for (int o = 32; o > 0; o >>= 1) { s += __shfl_xor(s, o); s2 += __shfl_xor(s2, o); }
  __shared__ float ls[4], ls2[4];
  if ((t & 63) == 0) { ls[t>>6] = s; ls2[t>>6] = s2; }
  __syncthreads();
  s  = ls[0]+ls[1]+ls[2]+ls[3];
  s2 = ls2[0]+ls2[1]+ls2[2]+ls2[3];
  const float mu  = s * (1.0f/Dm);
  const float var = s2 * (1.0f/Dm) - mu*mu;
  const float rs  = rsqrtf(var + 1e-5f);
  const float v0 = (x0-mu)*rs*w[t]     + b[t];
  const float v1 = (x1-mu)*rs*w[t+256] + b[t+256];
  const float v2 = (x2-mu)*rs*w[t+512] + b[t+512];
  if (OMODE == 0) {
    float* po = (float*)outp + (size_t)row * Dm;
    po[t] = v0; po[t+256] = v1; po[t+512] = v2;
  } else if (OMODE == 1) {
    uint32_t* po = (uint32_t*)outp + (size_t)row * Dm;
    po[t] = split_bf(v0); po[t+256] = split_bf(v1); po[t+512] = split_bf(v2);
  } else {
    unsigned short* po = (unsigned short*)outp + (size_t)row * Dm;
    po[t] = f2bf(v0); po[t+256] = f2bf(v1); po[t+512] = f2bf(v2);
  }
}

// ---------------- RoPE on fused qkv (stride QS): q at +0, k at +768 ----------------
__global__ __launch_bounds__(256)
void rope_kernel(float* __restrict__ qkv)
{
  const int gid = blockIdx.x * 256 + threadIdx.x;
  if (gid >= Tt * Hh * 32) return;
  const int tkn = gid / (Hh * 32);
  const int r   = gid - tkn * (Hh * 32);
  const int hh  = r >> 5;
  const int d   = r & 31;
  const int s   = tkn & 1023;
  const float freq = 1.0f / powf(10000.0f, (float)d * (1.0f/32.0f));
  const float ang  = (float)s * freq;
  const float c = cosf(ang), sn = sinf(ang);
  const size_t base = (size_t)tkn * QS + hh * DHd + d;
  float a1 = qkv[base], a2 = qkv[base + 32];
  qkv[base]      = a1*c - a2*sn;
  qkv[base + 32] = a1*sn + a2*c;
  float b1 = qkv[base + Dm], b2 = qkv[base + Dm + 32];
  qkv[base + Dm]      = b1*c - b2*sn;
  qkv[base + Dm + 32] = b1*sn + b2*c;
}

// ---------------- TTT chunked scan on fused qkv (stride QS); O packed to ob (stride Dm) ----------------
__global__ __launch_bounds__(256)
void ttt_scan_kernel(const float* __restrict__ qkv, uint32_t* __restrict__ ob)
{
  const int head = blockIdx.x >> 2;
  const int es   = blockIdx.x & 3;
  const int b  = head / Hh;
  const int hd = head % Hh;
  const int t  = threadIdx.x;
  __shared__ float Wm[64][17];
  __shared__ float kms[16][68];
  __shared__ float qms[16][68];
  __shared__ float Es[16][16];
  __shared__ float Asc[16][16];

  const int e   = t & 15;
  const int m16 = t >> 4;
  const int sr  = t >> 4;
  const int sc  = (t & 15) * 4;

  for (int i = t; i < 64*17; i += 256) ((float*)Wm)[i] = 0.0f;

  const int tb0 = b * 1024;
  const size_t gbase = (size_t)hd * DHd;
  float4 kr = *(const float4*)&qkv[(size_t)(tb0+sr)*QS + Dm   + gbase + sc];
  float4 qr = *(const float4*)&qkv[(size_t)(tb0+sr)*QS        + gbase + sc];
  __syncthreads();

  for (int c = 0; c < 64; ++c) {
    const int tb = tb0 + c*16;
    *(float4*)&kms[sr][sc] = kr;
    *(float4*)&qms[sr][sc] = qr;
    __syncthreads();
    if (c < 63) {
      kr = *(const float4*)&qkv[(size_t)(tb+16+sr)*QS + Dm   + gbase + sc];
      qr = *(const float4*)&qkv[(size_t)(tb+16+sr)*QS        + gbase + sc];
    }
    const float vreg = qkv[(size_t)(tb+m16)*QS + 2*Dm + gbase + es*16 + e];
    float aE = -vreg, aO = 0.0f;
    #pragma unroll
    for (int d = 0; d < 64; ++d) {
      const float w_ = Wm[d][e];
      aE += kms[m16][d] * w_;
      aO += qms[m16][d] * w_;
    }
    float aA = 0.0f;
    #pragma unroll
    for (int d = 0; d < 64; ++d) aA += qms[m16][d] * kms[e][d];
    Es[m16][e]  = aE;
    Asc[m16][e] = (e <= m16) ? (-ETA * aA) : 0.0f;
    __syncthreads();
    float acc = aO;
    #pragma unroll
    for (int n = 0; n < 16; ++n) acc += Asc[m16][n] * Es[n][e];
    ob[(size_t)(tb+m16)*Dm + gbase + es*16 + e] = split_bf(acc);
    #pragma unroll
    for (int j = 0; j < 4; ++j) {
      const int d = m16*4 + j;
      float a = 0.0f;
      #pragma unroll
      for (int m = 0; m < 16; ++m) a += kms[m][d] * Es[m][e];
      Wm[d][e] -= ETA * a;
    }
    __syncthreads();
  }
}

// ---------------- split-bf16 MFMA GEMM on PACKED operands, TM x TN tile ----------------
static __device__ __forceinline__ float gelu_f(float x){
  const float u = 0.7978845608028654f * (x + 0.044715f * x*x*x);
  return 0.5f * x * (1.0f + tanhf(u));
}

template<int TM, int TN, bool BIAS, bool GELU_, bool RES, bool PACKOUT>
__global__ __launch_bounds__(256)
void gemm_kernel(const uint32_t* __restrict__ A, const uint32_t* __restrict__ B,
                 const float* __restrict__ bias, const float* __restrict__ res,
                 void* __restrict__ Cp, int M, int N, int K)
{
  constexpr int FM = TM / 32;
  constexpr int FN = TN / 32;
  __shared__ __attribute__((aligned(16))) unsigned short AsH[TM][64];
  __shared__ __attribute__((aligned(16))) unsigned short AsL[TM][64];
  __shared__ __attribute__((aligned(16))) unsigned short BsH[TN][64];
  __shared__ __attribute__((aligned(16))) unsigned short BsL[TN][64];
  const int t    = threadIdx.x;
  const int lane = t & 63;
  const int fr   = lane & 15;
  const int fg   = lane >> 4;
  const int wave = t >> 6;
  const int wm   = (wave >> 1) * (TM/2);
  const int wn   = (wave & 1) * (TN/2);
  const int row0 = blockIdx.y * TM;
  const int n0   = blockIdx.x * TN;

  f32x4 acc[FM][FN];
  #pragma unroll
  for (int i = 0; i < FM; ++i)
    #pragma unroll
    for (int j = 0; j < FN; ++j)
      #pragma unroll
      for (int r = 0; r < 4; ++r) acc[i][j][r] = 0.0f;

  const int acol = (t & 3) * 16;
  const int kk2  = (t >> 6) * 16;

  for (int k0 = 0; k0 < K; k0 += 64) {
    #pragma unroll
    for (int r0 = 0; r0 < TM; r0 += 64) {
      const int arow = r0 + (t >> 2);
      const uint32_t* src = A + (size_t)(row0 + arow) * K + k0 + acol;
      #pragma unroll
      for (int i = 0; i < 2; ++i) {
        const uint4 p0 = *(const uint4*)(src + i*8);
        const uint4 p1 = *(const uint4*)(src + i*8 + 4);
        ushort8 uh, ul;
        uh[0]=(unsigned short)(p0.x>>16); ul[0]=(unsigned short)p0.x;
        uh[1]=(unsigned short)(p0.y>>16); ul[1]=(unsigned short)p0.y;
        uh[2]=(unsigned short)(p0.z>>16); ul[2]=(unsigned short)p0.z;
        uh[3]=(unsigned short)(p0.w>>16); ul[3]=(unsigned short)p0.w;
        uh[4]=(unsigned short)(p1.x>>16); ul[4]=(unsigned short)p1.x;
        uh[5]=(unsigned short)(p1.y>>16); ul[5]=(unsigned short)p1.y;
        uh[6]=(unsigned short)(p1.z>>16); ul[6]=(unsigned short)p1.z;
        uh[7]=(unsigned short)(p1.w>>16); ul[7]=(unsigned short)p1.w;
        const int byt = (arow*128 + acol*2 + i*16) ^ ((arow & 7) << 4);
        *(ushort8*)((char*)AsH + byt) = uh;
        *(ushort8*)((char*)AsL + byt) = ul;
      }
    }
    #pragma unroll
    for (int nb = 0; nb < TN; nb += 64) {
      const int bn = nb + (t & 63);
      uint32_t tp[16];
      #pragma unroll
      for (int i = 0; i < 16; ++i)
        tp[i] = B[(size_t)(k0 + kk2 + i) * N + n0 + bn];
      #pragma unroll
      for (int i = 0; i < 2; ++i) {
        ushort8 uh, ul;
        #pragma unroll
        for (int j = 0; j < 8; ++j) {
          const uint32_t p = tp[i*8 + j];
          uh[j] = (unsigned short)(p >> 16);
          ul[j] = (unsigned short)p;
        }
        const int byt = (bn*128 + kk2*2 + i*16) ^ ((bn & 7) << 4);
        *(ushort8*)((char*)BsH + byt) = uh;
        *(ushort8*)((char*)BsL + byt) = ul;
      }
    }
    __syncthreads();
    #pragma unroll
    for (int kh = 0; kh < 2; ++kh) {
      bf16x8 ah[FM], al[FM], bh[FN], bl[FN];
      const int swz = (fr & 7) << 4;
      #pragma unroll
      for (int mt = 0; mt < FM; ++mt) {
        const int byt = ((wm + mt*16 + fr)*128 + kh*64 + fg*16) ^ swz;
        ah[mt] = *(const bf16x8*)((const char*)AsH + byt);
        al[mt] = *(const bf16x8*)((const char*)AsL + byt);
      }
      #pragma unroll
      for (int nt = 0; nt < FN; ++nt) {
        const int byt = ((wn + nt*16 + fr)*128 + kh*64 + fg*16) ^ swz;
        bh[nt] = *(const bf16x8*)((const char*)BsH + byt);
        bl[nt] = *(const bf16x8*)((const char*)BsL + byt);
      }
      #pragma unroll
      for (int mt = 0; mt < FM; ++mt)
        #pragma unroll
        for (int nt = 0; nt < FN; ++nt) {
          acc[mt][nt] = __builtin_amdgcn_mfma_f32_16x16x32_bf16(ah[mt], bh[nt], acc[mt][nt], 0, 0, 0);
          acc[mt][nt] = __builtin_amdgcn_mfma_f32_16x16x32_bf16(ah[mt], bl[nt], acc[mt][nt], 0, 0, 0);
          acc[mt][nt] = __builtin_amdgcn_mfma_f32_16x16x32_bf16(al[mt], bh[nt], acc[mt][nt], 0, 0, 0);
        }
    }
    __syncthreads();
  }

  #pragma unroll
  for (int mt = 0; mt < FM; ++mt) {
    #pragma unroll
    for (int nt = 0; nt < FN; ++nt) {
      const int col = n0 + wn + nt*16 + fr;
      const int rbase = row0 + wm + mt*16 + fg*4;
      const float bcol = BIAS ? bias[col] : 0.0f;
      #pragma unroll
      for (int r = 0; r < 4; ++r) {
        float val = acc[mt][nt][r];
        if (BIAS)  val += bcol;
        if (GELU_) val = gelu_f(val);
        const size_t off = (size_t)(rbase + r) * N + col;
        if (PACKOUT) {
          ((uint32_t*)Cp)[off] = split_bf(val);
        } else {
          if (RES) val += res[off];
          ((float*)Cp)[off] = val;
        }
      }
    }
  }
}

// ---------------- logits GEMM: 128x128 tile, C = hbf @ tokB^T ----------------
// PRE=1: tokb = pre-converted bf16 rows. PRE=0: convert from tok f32 in staging.
template<bool PRE>
__global__ __launch_bounds__(256)
void logits_kernel(const unsigned short* __restrict__ hbf, const float* __restrict__ tok,
                   const unsigned short* __restrict__ tokb, float* __restrict__ C)
{
  __shared__ __attribute__((aligned(16))) unsigned short As[128*64];
  __shared__ __attribute__((aligned(16))) unsigned short Bs[128*64];
  int bid = blockIdx.x;
  bid = (bid & 7) * 1572 + (bid >> 3);       // XCD swizzle: 12576/8 = 1572
  const int n0   = (bid >> 5) * 128;
  const int row0 = (bid & 31) * 128;

  const int t    = threadIdx.x;
  const int lane = t & 63;
  const int fr   = lane & 15;
  const int fg   = lane >> 4;
  const int wave = t >> 6;
  const int wm   = (wave >> 1) * 64;
  const int wn   = (wave & 1) * 64;

  const int arow = t >> 1;
  const int ach  = (t & 1) * 32;

  f32x4 acc[4][4];
  #pragma unroll
  for (int i = 0; i < 4; ++i)
    #pragma unroll
    for (int j = 0; j < 4; ++j)
      #pragma unroll
      for (int r = 0; r < 4; ++r) acc[i][j][r] = 0.0f;

  for (int ks = 0; ks < 12; ++ks) {
    { // stage A
      const unsigned short* src = &hbf[(size_t)(row0 + arow) * Dm + ks*64 + ach];
      #pragma unroll
      for (int i = 0; i < 4; ++i) {
        const ushort8 u = *(const ushort8*)(src + i*8);
        const int byt = (arow*128 + (ach + i*8)*2) ^ ((arow & 7) << 4);
        *(ushort8*)((char*)As + byt) = u;
      }
    }
    { // stage B
      const int brow = n0 + arow;
      if (brow < Vv) {
        if (PRE) {
          const unsigned short* src = &tokb[(size_t)brow * Dm + ks*64 + ach];
          #pragma unroll
          for (int i = 0; i < 4; ++i) {
            const ushort8 u = *(const ushort8*)(src + i*8);
            const int byt = (arow*128 + (ach + i*8)*2) ^ ((arow & 7) << 4);
            *(ushort8*)((char*)Bs + byt) = u;
          }
        } else {
          const float* src = &tok[(size_t)brow * Dm + ks*64 + ach];
          #pragma unroll
          for (int i = 0; i < 4; ++i) {
            const float4 f0 = *(const float4*)(src + i*8);
            const float4 f1 = *(const float4*)(src + i*8 + 4);
            ushort8 u;
            u[0]=f2bf_rhu(f0.x); u[1]=f2bf_rhu(f0.y); u[2]=f2bf_rhu(f0.z); u[3]=f2bf_rhu(f0.w);
            u[4]=f2bf_rhu(f1.x); u[5]=f2bf_rhu(f1.y); u[6]=f2bf_rhu(f1.z); u[7]=f2bf_rhu(f1.w);
            const int byt = (arow*128 + (ach + i*8)*2) ^ ((arow & 7) << 4);
            *(ushort8*)((char*)Bs + byt) = u;
          }
        }
      } else {
        ushort8 z;
        #pragma unroll
        for (int j = 0; j < 8; ++j) z[j] = 0;
        #pragma unroll
        for (int i = 0; i < 4; ++i) {
          const int byt = (arow*128 + (ach + i*8)*2) ^ ((arow & 7) << 4);
          *(ushort8*)((char*)Bs + byt) = z;
        }
      }
    }
    __syncthreads();
    #pragma unroll
    for (int kh = 0; kh < 2; ++kh) {
      bf16x8 af[4], bfr[4];
      const int swz = (fr & 7) << 4;
      #pragma unroll
      for (int mt = 0; mt < 4; ++mt)
        af[mt] = *(const bf16x8*)((const char*)As + (((wm + mt*16 + fr)*128 + kh*64 + fg*16) ^ swz));
      #pragma unroll
      for (int nt = 0; nt < 4; ++nt)
        bfr[nt] = *(const bf16x8*)((const char*)Bs + (((wn + nt*16 + fr)*128 + kh*64 + fg*16) ^ swz));
      #pragma unroll
      for (int mt = 0; mt < 4; ++mt)
        #pragma unroll
        for (int nt = 0; nt < 4; ++nt)
          acc[mt][nt] = __builtin_amdgcn_mfma_f32_16x16x32_bf16(af[mt], bfr[nt], acc[mt][nt], 0, 0, 0);
    }
    __syncthreads();
  }

  #pragma unroll
  for (int mt = 0; mt < 4; ++mt) {
    #pragma unroll
    for (int nt = 0; nt < 4; ++nt) {
      const int col = n0 + wn + nt*16 + fr;
      if (col < Vv) {
        const int rbase = row0 + wm + mt*16 + fg*4;
        #pragma unroll
        for (int r = 0; r < 4; ++r)
          C[(size_t)(rbase + r) * Vv + col] = acc[mt][nt][r];
      }
    }
  }
}

// ---------------- host-side orchestration ----------------
extern "C" void kernel_launch(void* const* d_in, const int* in_sizes, int n_in,
                              void* d_out, int out_size, void* d_ws, size_t ws_size,
                              hipStream_t stream)
{
  const int*   ids = (const int*)  d_in[0];
  const float* tok = (const float*)d_in[1];
  const float* ew  = (const float*)d_in[2];
  const float* eb  = (const float*)d_in[3];
  const float* wq  = (const float*)d_in[4];
  const float* wk  = (const float*)d_in[5];
  const float* wv  = (const float*)d_in[6];
  const float* wo  = (const float*)d_in[7];
  const float* n1w = (const float*)d_in[8];
  const float* n1b = (const float*)d_in[9];
  const float* n2w = (const float*)d_in[10];
  const float* n2b = (const float*)d_in[11];
  const float* m1w = (const float*)d_in[12];
  const float* m1b = (const float*)d_in[13];
  const float* m2w = (const float*)d_in[14];
  const float* m2b = (const float*)d_in[15];
  const float* onw = (const float*)d_in[16];
  const float* onb = (const float*)d_in[17];

  float* x = (float*)d_ws;
  float* h = x + (size_t)Tt * Dm;
  // optional tok-bf16 area in ws (runtime-checked)
  const size_t ws_need = (size_t)2*Tt*Dm*4 + (size_t)Vv*Dm*2;
  const bool pre = (ws_size >= ws_need);
  unsigned short* tokb = (unsigned short*)((char*)d_ws + (size_t)2*Tt*Dm*4);

  float* out = (float*)d_out;
  uint32_t* g   = (uint32_t*)d_out;                  // packed g [4096][3072]
  float*    qkv = out + (size_t)(1u << 24);          // [4096][2304] f32
  uint32_t* ob  = (uint32_t*)(out + (size_t)27000000u); // packed [4096][768]
  uint32_t* wpk = (uint32_t*)d_out + 40000000u;
  const size_t SQQ = (size_t)Ll * Dm * Dm;           // 7,077,888
  const size_t SMM = (size_t)Ll * Dm * Ff;           // 28,311,552
  uint32_t* qkv_pk = wpk;                            // [L][768][2304] = 3*SQQ
  uint32_t* wo_pk  = qkv_pk + 3*SQQ;
  uint32_t* m1_pk  = wo_pk  + SQQ;
  uint32_t* m2_pk  = m1_pk  + SMM;

  convw_kernel<<<1024, 256, 0, stream>>>(wq, qkv_pk, (int)(SQQ/4), Dm, QS, 0);
  convw_kernel<<<1024, 256, 0, stream>>>(wk, qkv_pk, (int)(SQQ/4), Dm, QS, Dm);
  convw_kernel<<<1024, 256, 0, stream>>>(wv, qkv_pk, (int)(SQQ/4), Dm, QS, 2*Dm);
  convw_kernel<<<1024, 256, 0, stream>>>(wo, wo_pk,  (int)(SQQ/4), Dm, Dm, 0);
  convw_kernel<<<2048, 256, 0, stream>>>(m1w, m1_pk, (int)(SMM/4), Ff, Ff, 0);
  convw_kernel<<<2048, 256, 0, stream>>>(m2w, m2_pk, (int)(SMM/4), Dm, Dm, 0);
  if (pre) convtok_kernel<<<2048, 256, 0, stream>>>(tok, tokb, Vv*Dm/8);

  ln_kernel<0><<<Tt, 256, 0, stream>>>(tok, ids, ew, eb, x);

  for (int l = 0; l < Ll; ++l) {
    ln_kernel<1><<<Tt, 256, 0, stream>>>(x, nullptr, n1w + l*Dm, n1b + l*Dm, h);
    gemm_kernel<128,128,false,false,false,false><<<dim3(QS/128, Tt/128), 256, 0, stream>>>(
        (const uint32_t*)h, qkv_pk + (size_t)l*Dm*QS, nullptr, nullptr, qkv, Tt, QS, Dm);
    rope_kernel<<<6144, 256, 0, stream>>>(qkv);
    ttt_scan_kernel<<<192, 256, 0, stream>>>(qkv, ob);
    gemm_kernel<128,64,false,false,true,false><<<dim3(Dm/64, Tt/128), 256, 0, stream>>>(
        ob, wo_pk + (size_t)l*Dm*Dm, nullptr, x, x, Tt, Dm, Dm);
    ln_kernel<1><<<Tt, 256, 0, stream>>>(x, nullptr, n2w + l*Dm, n2b + l*Dm, h);
    gemm_kernel<128,128,true,true,false,true><<<dim3(Ff/128, Tt/128), 256, 0, stream>>>(
        (const uint32_t*)h, m1_pk + (size_t)l*Dm*Ff, m1b + (size_t)l*Ff, nullptr, g, Tt, Ff, Dm);
    gemm_kernel<128,64,true,false,true,false><<<dim3(Dm/64, Tt/128), 256, 0, stream>>>(
        g, m2_pk + (size_t)l*Ff*Dm, m2b + (size_t)l*Dm, x, x, Tt, Dm, Ff);
  }

  ln_kernel<2><<<Tt, 256, 0, stream>>>(x, nullptr, onw, onb, h);
  if (pre)
    logits_kernel<true><<<dim3(12576, 1), 256, 0, stream>>>((const unsigned short*)h, tok, tokb, out);
  else
    logits_kernel<false><<<dim3(12576, 1), 256, 0, stream>>>((const unsigned short*)h, tok, nullptr, out);
}